// Round 11
// baseline (533.855 us; speedup 1.0000x reference)
//
#include <hip/hip_runtime.h>
#include <hip/hip_bf16.h>

// ---------------- problem constants ----------------
#define BB   128
#define SS   2048
#define NPOS 262144L   // BB*SS
#define MM   50
#define DK   64
#define DV   128
#define DS   50
#define KN   5
#define NQ   1000      // distinct questions
#define NC   16        // scan chunks
#define LC   128       // SS/NC

// ---------------- workspace layout (byte offsets) ----------------
#define ATTNQ_OFF  262144L      // fp32 [1000][64] attn rows (softmaxed), cols 50..63 = 0
#define PREQ_OFF   524288L      // fp32 [1000][52] q_e-part of summary (incl. bias)
#define ALQ_OFF    786432L      // fp32 [1000] softplus alpha
#define BQ_OFF     790528L      // fp32 [1000][4] beta
#define EAQ_OFF    1048576L     // fp32 [5000][128][2] interleaved (e,a) pairs
#define GIDX_OFF   6168576L     // int2 [NPOS+6] {(q*5+r)*256, q*64}
#define CC_OFF     75497472L    // bf16 [NC][B][50][128]
#define DC_OFF     101711872L   // bf16 [NC][B][50][128]
#define WS_NEEDED  127926272L

// fp32 weight block offsets (floats) -- only what the k3-phase needs
#define SWo   12160   // summary_w TRANSPOSED [50][192]
#define TWo   21810   // theta_w [50]
#define SCo   22180   // [0]=theta_b

// kfront block ranges
#define KIDX_NB  1024
#define KQ_NB    4
#define KEAR_NB  2500
#define KPREP_NB 1
#define KFRONT_NB (KIDX_NB + KQ_NB + KEAR_NB + KPREP_NB)   // 3529

// LDS tile stride (u16): 130 = 65 dwords (odd) -> transpose reads hit bank v%32
#define TSTR 130

typedef unsigned short u16;
typedef __attribute__((ext_vector_type(8))) short   short8;
typedef __attribute__((ext_vector_type(4))) float   floatx4;
typedef __attribute__((ext_vector_type(2))) float   float2v;
typedef __attribute__((ext_vector_type(2))) int     int2v;

static __device__ __forceinline__ float b2f(u16 u) {
    union { unsigned int i; float f; } x; x.i = ((unsigned int)u) << 16; return x.f;
}
static __device__ __forceinline__ u16 f2b(float f) {
    union { float f; unsigned int i; } x; x.f = f;
    unsigned int i = x.i;
    return (u16)((i + 0x7fffu + ((i >> 16) & 1u)) >> 16);
}
static __device__ __forceinline__ float fast_tanh(float x) {
    float xc = fminf(15.f, fmaxf(-15.f, x));
    float t = __expf(2.f * xc);
    return (t - 1.f) / (t + 1.f);
}
static __device__ __forceinline__ float2v splat2(float x) {
    return (float2v){x, x};
}
static __device__ __forceinline__ float2v vfma(float2v a, float2v b, float2v c) {
    return __builtin_elementwise_fma(a, b, c);   // v_pk_fma_f32
}
static __device__ __forceinline__ int rfl(int x) {
    return __builtin_amdgcn_readfirstlane(x);
}

// ---------------- kfront: fused kidx + kq + kear + kprep ----------------
__global__ __launch_bounds__(256) void kfront(
    const int* __restrict__ questions, const int* __restrict__ responses,
    const float* __restrict__ qe_w, const float* __restrict__ iv_w,
    const float* __restrict__ vpw, const float* __restrict__ vpb,
    const float* __restrict__ km, const float* __restrict__ sw,
    const float* __restrict__ sb, const float* __restrict__ aw,
    const float* __restrict__ ab, const float* __restrict__ bw,
    const float* __restrict__ bb, const float* __restrict__ ew_,
    const float* __restrict__ adw_, const float* __restrict__ eb,
    const float* __restrict__ adb, const float* __restrict__ tw,
    const float* __restrict__ tb,
    int2v* __restrict__ gidx, float* __restrict__ attnq,
    float* __restrict__ preq, float* __restrict__ alq,
    float* __restrict__ bq, float* __restrict__ eaq,
    float* __restrict__ wf)
{
    int bid = blockIdx.x;
    int tid = threadIdx.x;

    if (bid < KIDX_NB) {
        // ---- kidx: per-position index table (+6 pad entries) ----
        long pos = (long)bid * 256 + tid;
        int q = questions[pos], r = responses[pos];
        int2v g = { (q * 5 + r) * 256, q * 64 };
        gidx[pos] = g;
        if (pos == NPOS - 1) {
            #pragma unroll
            for (int p = 0; p < 6; ++p) gidx[NPOS + p] = g;   // prefetch pads
        }
        return;
    }

    if (bid < KIDX_NB + KQ_NB) {
        // ---- kq: per-question tables (lane = q), raw weight reads ----
        int q = (bid - KIDX_NB) * 256 + tid;
        if (q >= NQ) return;

        float qe[64];
        const float* qrow = qe_w + (long)q * 64;
        #pragma unroll
        for (int c = 0; c < 16; ++c) {
            floatx4 vv = *(const floatx4*)(qrow + c * 4);
            qe[c*4+0] = vv[0]; qe[c*4+1] = vv[1]; qe[c*4+2] = vv[2]; qe[c*4+3] = vv[3];
        }
        float lg[50];
        #pragma unroll 2
        for (int m = 0; m < 50; ++m) {
            float acc = 0.f;
            #pragma unroll
            for (int k = 0; k < 64; ++k) acc = fmaf(qe[k], km[m * 64 + k], acc);
            lg[m] = acc;
        }
        float mx = -1e30f;
        #pragma unroll
        for (int m = 0; m < 50; ++m) mx = fmaxf(mx, lg[m]);
        float sum = 0.f;
        #pragma unroll
        for (int m = 0; m < 50; ++m) { lg[m] = __expf(lg[m] - mx); sum += lg[m]; }
        float inv = 1.f / sum;
        float* adst = attnq + q * 64;
        #pragma unroll
        for (int m = 0; m < 50; ++m) adst[m] = lg[m] * inv;
        #pragma unroll
        for (int m = 50; m < 64; ++m) adst[m] = 0.f;

        float* pdst = preq + q * 52;
        #pragma unroll 2
        for (int j = 0; j < 50; ++j) {
            float acc = sb[j];
            #pragma unroll
            for (int k = 0; k < 64; ++k)
                acc = fmaf(qe[k], sw[(128 + k) * 50 + j], acc);   // sw_t[j][128+k]
            pdst[j] = acc;
        }
        pdst[50] = 0.f; pdst[51] = 0.f;

        float al = ab[0];
        #pragma unroll
        for (int k = 0; k < 64; ++k) al = fmaf(qe[k], aw[k], al);
        alq[q] = (al > 20.f) ? al : log1pf(__expf(al));
        #pragma unroll
        for (int j = 0; j < 4; ++j) {
            float acc = bb[j];
            #pragma unroll
            for (int k = 0; k < 64; ++k) acc = fmaf(qe[k], bw[k * 4 + j], acc);
            bq[q * 4 + j] = acc;
        }
        return;
    }

    if (bid < KIDX_NB + KQ_NB + KEAR_NB) {
        // ---- kear: 2 qr rows per block, raw transposed-column reads (coalesced) ----
        __shared__ float vL[2][128];
        int half = tid >> 7;               // 0/1
        int j = tid & 127;
        int qr = (bid - KIDX_NB - KQ_NB) * 2 + half;
        int q = qr / 5, r = qr - q * 5;

        const float* irow = iv_w + (long)q * 64;       // broadcast
        float acc = vpb[j];
        #pragma unroll
        for (int k = 0; k < 64; ++k)
            acc = fmaf(irow[k], vpw[k * 128 + j], acc);          // coalesced across j
        #pragma unroll
        for (int kk = 0; kk < KN; ++kk) {
            float rf = fmaxf(1.f - fabsf((float)kk - (float)r) * 0.25f, 0.f);
            acc = fmaf(rf, vpw[(64 + kk) * 128 + j], acc);
        }
        vL[half][j] = acc;
        __syncthreads();

        float ea = eb[j], aa = adb[j];
        #pragma unroll
        for (int k = 0; k < 128; ++k) {
            float v = vL[half][k];                      // broadcast
            ea = fmaf(v, ew_[k * 128 + j], ea);         // coalesced across j
            aa = fmaf(v, adw_[k * 128 + j], aa);
        }
        float* dst = eaq + (long)qr * 256;
        dst[2 * j]     = 1.f / (1.f + __expf(-ea));   // e
        dst[2 * j + 1] = fast_tanh(aa);               // a
        return;
    }

    // ---- kprep range: k3-phase tables (sw transpose + theta) ----
    {
        for (int i = tid; i < 9600; i += 256) {           // sw_t[j][k] = sw[k][j]
            int j = i / 192, k = i - j * 192;
            wf[SWo + i] = sw[k * 50 + j];
        }
        for (int i = tid; i < 50; i += 256) wf[TWo + i] = tw[i];
        if (tid == 0) wf[SCo + 0] = tb[0];
    }
}

// ---------------- kp1: per-chunk affine transfer function ----------------
// Measured-best R8 structure (142us attractor): 256 thr = 4 waves; wave-half
// mh owns pairs [0..12]/[12..24] (pair 12 idempotent-duplicated). Decoupled
// prefetch queues: gidx@t+6 -> offsets -> ea@t+4.
__global__ __launch_bounds__(256) __attribute__((amdgpu_waves_per_eu(5, 8)))
void kp1(
    const int2v* __restrict__ gidx, const float* __restrict__ attnq,
    const float* __restrict__ eaq,
    u16* __restrict__ Cc, u16* __restrict__ Dc)
{
    int b = blockIdx.x & (BB - 1);
    int c = blockIdx.x >> 7;
    int tid = threadIdx.x;
    int v = tid & 127;
    int mh = rfl(tid >> 7);
    int base = mh * 12;
    long tb = (long)b * SS + (long)c * LC;
    const int2v* gx = gidx + tb;

    float2v C[13], D[13];
    #pragma unroll
    for (int i = 0; i < 13; ++i) { C[i] = splat2(1.f); D[i] = splat2(0.f); }

    int eo0 = rfl(gx[0].x), ao0 = rfl(gx[0].y);
    int eo1 = rfl(gx[1].x), ao1 = rfl(gx[1].y);
    int eo2 = rfl(gx[2].x), ao2 = rfl(gx[2].y);
    int eo3 = rfl(gx[3].x), ao3 = rfl(gx[3].y);
    int eo4 = rfl(gx[4].x), ao4 = rfl(gx[4].y);
    int eo5 = rfl(gx[5].x), ao5 = rfl(gx[5].y);
    float2v ea0 = *(const float2v*)(eaq + eo0 + 2 * v);
    float2v ea1 = *(const float2v*)(eaq + eo1 + 2 * v);
    float2v ea2 = *(const float2v*)(eaq + eo2 + 2 * v);
    float2v ea3 = *(const float2v*)(eaq + eo3 + 2 * v);
    float2v wA[13], wB[13];
    {
        const float2v* a0 = (const float2v*)(attnq + ao0) + base;
        const float2v* a1 = (const float2v*)(attnq + ao1) + base;
        #pragma unroll
        for (int i = 0; i < 13; ++i) { wA[i] = a0[i]; wB[i] = a1[i]; }
    }

    for (int t = 0; t < LC; t += 2) {
        float2v ea4 = *(const float2v*)(eaq + eo4 + 2 * v);
        float2v ea5 = *(const float2v*)(eaq + eo5 + 2 * v);
        int2v g6 = gx[t + 6], g7 = gx[t + 7];
        int eo6 = rfl(g6.x), ao6 = rfl(g6.y);
        int eo7 = rfl(g7.x), ao7 = rfl(g7.y);
        const float2v* aw2 = (const float2v*)(attnq + ao2) + base;
        const float2v* aw3 = (const float2v*)(attnq + ao3) + base;
        // ---- even step: ea0, wA ----
        {
            float2v ne2 = splat2(-ea0.x), a2 = splat2(ea0.y);
            #pragma unroll
            for (int i = 0; i < 13; ++i) {
                float2v tD = vfma(ne2, D[i], a2);   // a - e*D
                float2v tC = ne2 * C[i];            // -e*C
                D[i] = vfma(wA[i], tD, D[i]);       // D + w*(a - e*D)
                C[i] = vfma(wA[i], tC, C[i]);       // C - w*e*C
            }
        }
        #pragma unroll
        for (int i = 0; i < 13; ++i) wA[i] = aw2[i];
        // ---- odd step: ea1, wB ----
        {
            float2v ne2 = splat2(-ea1.x), a2 = splat2(ea1.y);
            #pragma unroll
            for (int i = 0; i < 13; ++i) {
                float2v tD = vfma(ne2, D[i], a2);
                float2v tC = ne2 * C[i];
                D[i] = vfma(wB[i], tD, D[i]);
                C[i] = vfma(wB[i], tC, C[i]);
            }
        }
        #pragma unroll
        for (int i = 0; i < 13; ++i) wB[i] = aw3[i];
        ea0 = ea2; ea1 = ea3; ea2 = ea4; ea3 = ea5;
        ao2 = ao4; ao3 = ao5;
        eo4 = eo6; eo5 = eo7; ao4 = ao6; ao5 = ao7;
    }

    long o = ((long)(c * BB + b) * 50) * 128 + v;
    #pragma unroll
    for (int i = 0; i < 13; ++i) {
        int ii = base + i;                         // pair 12 written twice, same value
        Cc[o + (long)(2*ii)   * 128] = f2b(C[i].x);
        Cc[o + (long)(2*ii+1) * 128] = f2b(C[i].y);
        Dc[o + (long)(2*ii)   * 128] = f2b(D[i].x);
        Dc[o + (long)(2*ii+1) * 128] = f2b(D[i].y);
    }
}

// ---------------- kcomb: sequential chunk combine -> start states (into Cc) ----------------
__global__ __launch_bounds__(256) void kcomb(
    u16* __restrict__ Cc, const u16* __restrict__ Dc,
    const float* __restrict__ init_mem)
{
    long p = (long)blockIdx.x * 256 + threadIdx.x;   // over B*3200 bf16-pairs
    if (p >= (long)BB * 3200) return;
    int pv = (int)(p % 3200);
    int b  = (int)(p / 3200);
    float2v s = *(const float2v*)(init_mem + 2 * pv);
    long stride = (long)BB * 6400;
    long o = (long)b * 6400 + 2 * pv;

    unsigned int cv[NC], dv[NC];
    #pragma unroll
    for (int c = 0; c < NC; ++c) {
        cv[c] = *(const unsigned int*)(Cc + c * stride + o);
        dv[c] = *(const unsigned int*)(Dc + c * stride + o);
    }
    #pragma unroll
    for (int c = 0; c < NC; ++c) {
        float C0 = b2f((u16)(cv[c] & 0xffffu)), C1 = b2f((u16)(cv[c] >> 16));
        float D0 = b2f((u16)(dv[c] & 0xffffu)), D1 = b2f((u16)(dv[c] >> 16));
        unsigned int sp = (unsigned int)f2b(s.x) | ((unsigned int)f2b(s.y) << 16);
        *(unsigned int*)(Cc + c * stride + o) = sp;  // chunk-start state
        s.x = fmaf(C0, s.x, D0);
        s.y = fmaf(C1, s.y, D1);
    }
}

// ---------------- kp2f: replay chunk -> LDS tile -> fused k3 epilogue ----------------
// Phase 1: thread owns M[25]; per-step read values land in an LDS tile
// tile[t*TSTR + v] (u16 bf16, identical f2b as before) -- NO global ws_reads.
// Phase 2: one barrier, thread v reads ITS row (t=v) from LDS as b32 pairs
// (stride 130 u16 = 65 dwords, odd -> lane v hits bank v%32: conflict-free
// transpose), then summary/theta/logits math.
// Deletes 67MB write + 67MB re-fetch and the vmcnt store pressure in phase 1.
__global__ __launch_bounds__(128) __attribute__((amdgpu_waves_per_eu(3, 8)))
void kp2f(
    const int2v* __restrict__ gidx, const float* __restrict__ attnq,
    const float* __restrict__ eaq,
    const u16* __restrict__ Sc,
    const int* __restrict__ questions, const float* __restrict__ wf,
    const float* __restrict__ preq, const float* __restrict__ alq,
    const float* __restrict__ bq, float* __restrict__ out)
{
    __shared__ u16 tile[LC * TSTR];      // 33280 B: [t][v] bf16 reads
    __shared__ float stg[1280];          // [0,640) logits | [640,1280) probs
    int b = blockIdx.x & (BB - 1);
    int c = blockIdx.x >> 7;
    int v = threadIdx.x;
    long tb = (long)b * SS + (long)c * LC;
    const int2v* gx = gidx + tb;

    float2v M[25];
    {
        long o = ((long)(c * BB + b) * 50) * 128 + v;
        #pragma unroll
        for (int i = 0; i < 25; ++i)
            M[i] = (float2v){ b2f(Sc[o + (long)(2*i) * 128]),
                              b2f(Sc[o + (long)(2*i+1) * 128]) };
    }

    int eo0 = rfl(gx[0].x), ao0 = rfl(gx[0].y);
    int eo1 = rfl(gx[1].x), ao1 = rfl(gx[1].y);
    int eo2 = rfl(gx[2].x), ao2 = rfl(gx[2].y);
    int eo3 = rfl(gx[3].x), ao3 = rfl(gx[3].y);
    int eo4 = rfl(gx[4].x), ao4 = rfl(gx[4].y);
    int eo5 = rfl(gx[5].x), ao5 = rfl(gx[5].y);
    float2v ea0 = *(const float2v*)(eaq + eo0 + 2 * v);
    float2v ea1 = *(const float2v*)(eaq + eo1 + 2 * v);
    float2v ea2 = *(const float2v*)(eaq + eo2 + 2 * v);
    float2v ea3 = *(const float2v*)(eaq + eo3 + 2 * v);
    float2v wA[25], wB[25];
    {
        const float2v* a0 = (const float2v*)(attnq + ao0);
        const float2v* a1 = (const float2v*)(attnq + ao1);
        #pragma unroll
        for (int i = 0; i < 25; ++i) { wA[i] = a0[i]; wB[i] = a1[i]; }
    }

    for (int t = 0; t < LC; t += 2) {
        float2v ea4 = *(const float2v*)(eaq + eo4 + 2 * v);
        float2v ea5 = *(const float2v*)(eaq + eo5 + 2 * v);
        int2v g6 = gx[t + 6], g7 = gx[t + 7];
        int eo6 = rfl(g6.x), ao6 = rfl(g6.y);
        int eo7 = rfl(g7.x), ao7 = rfl(g7.y);
        const float2v* aw2 = (const float2v*)(attnq + ao2);
        const float2v* aw3 = (const float2v*)(attnq + ao3);
        // ---- even step: ea0, wA ----
        {
            float2v ne2 = splat2(-ea0.x), a2 = splat2(ea0.y);
            float2v r0 = splat2(0.f), r1 = splat2(0.f);
            #pragma unroll
            for (int i = 0; i < 25; ++i) {
                float2v tM = vfma(ne2, M[i], a2);        // a - e*M
                if (i & 1) r1 = vfma(wA[i], M[i], r1);   // read accum (pre-update)
                else       r0 = vfma(wA[i], M[i], r0);
                M[i] = vfma(wA[i], tM, M[i]);            // M + w*(a - e*M)
            }
            float2v rs = r0 + r1;
            tile[t * TSTR + v] = f2b(rs.x + rs.y);       // LDS, conflict-free
        }
        #pragma unroll
        for (int i = 0; i < 25; ++i) wA[i] = aw2[i];     // refill for t+2
        // ---- odd step: ea1, wB ----
        {
            float2v ne2 = splat2(-ea1.x), a2 = splat2(ea1.y);
            float2v r0 = splat2(0.f), r1 = splat2(0.f);
            #pragma unroll
            for (int i = 0; i < 25; ++i) {
                float2v tM = vfma(ne2, M[i], a2);
                if (i & 1) r1 = vfma(wB[i], M[i], r1);
                else       r0 = vfma(wB[i], M[i], r0);
                M[i] = vfma(wB[i], tM, M[i]);
            }
            float2v rs = r0 + r1;
            tile[(t + 1) * TSTR + v] = f2b(rs.x + rs.y);
        }
        #pragma unroll
        for (int i = 0; i < 25; ++i) wB[i] = aw3[i];     // refill for t+3
        ea0 = ea2; ea1 = ea3; ea2 = ea4; ea3 = ea5;
        ao2 = ao4; ao3 = ao5;
        eo4 = eo6; eo5 = eo7; ao4 = ao6; ao5 = ao7;
    }

    // ================= fused k3 phase =================
    __syncthreads();                 // tile complete

    long pos = tb + v;               // this thread's position (t = v row)
    int q = questions[pos];
    const float* swt = wf + SWo;
    const float* pq = preq + q * 52;

    // transpose read from LDS: row v, b32 pairs; lane v -> bank v%32 (stride 65 dwords)
    float2v ch2[64];
    {
        const u16* trow = tile + v * TSTR;
        #pragma unroll
        for (int k = 0; k < 64; ++k) {
            unsigned int d = *(const unsigned int*)(trow + 2 * k);   // 4B-aligned
            ch2[k] = (float2v){ b2f((u16)(d & 0xffffu)), b2f((u16)(d >> 16)) };
        }
    }

    float dot = 0.f;
    #pragma unroll 2
    for (int j = 0; j < 50; ++j) {
        const float2v* sw2 = (const float2v*)(swt + j * 192);   // uniform
        float2v a2 = splat2(0.f), a3 = splat2(0.f);             // 2 chains
        #pragma unroll
        for (int k = 0; k < 64; k += 2) {
            a2 = vfma(ch2[k],     sw2[k],     a2);
            a3 = vfma(ch2[k + 1], sw2[k + 1], a3);
        }
        float a = pq[j] + a2.x + a2.y + a3.x + a3.y;            // q_e part precomputed
        dot = fmaf(fast_tanh(a), wf[TWo + j], dot);
    }
    float theta = fast_tanh(dot + wf[SCo + 0]);
    float alpha = alq[q];
    floatx4 bet = *(const floatx4*)(bq + q * 4);

    float inter = theta * alpha;
    float l1 = inter - bet[0];
    float l2 = l1 + inter - bet[1];
    float l3 = l2 + inter - bet[2];
    float l4 = l3 + inter - bet[3];
    float mx = fmaxf(0.f, fmaxf(fmaxf(l1, l2), fmaxf(l3, l4)));
    float e0 = __expf(0.f - mx), e1 = __expf(l1 - mx), e2 = __expf(l2 - mx);
    float e3 = __expf(l3 - mx), e4 = __expf(l4 - mx);
    float inv = 1.f / (e0 + e1 + e2 + e3 + e4);

    out[pos] = theta;                                   // coalesced
    out[NPOS + pos] = alpha;                            // coalesced
    *(floatx4*)(out + 2L * NPOS + pos * 4) = bet;       // dwordx4, contiguous

    stg[v * 5 + 0] = 0.f;
    stg[v * 5 + 1] = l1;  stg[v * 5 + 2] = l2;
    stg[v * 5 + 3] = l3;  stg[v * 5 + 4] = l4;
    stg[640 + v * 5 + 0] = e0 * inv;
    stg[640 + v * 5 + 1] = e1 * inv;
    stg[640 + v * 5 + 2] = e2 * inv;
    stg[640 + v * 5 + 3] = e3 * inv;
    stg[640 + v * 5 + 4] = e4 * inv;
    __syncthreads();
    float* ol = out + 6L * NPOS + tb * 5;               // block's 640-float tile
    float* op = out + 11L * NPOS + tb * 5;
    #pragma unroll
    for (int i = 0; i < 5; ++i) {
        ol[i * 128 + v] = stg[i * 128 + v];             // coalesced dwords
        op[i * 128 + v] = stg[640 + i * 128 + v];       // coalesced dwords
    }
}

// ---------------- host launcher ----------------
extern "C" void kernel_launch(void* const* d_in, const int* in_sizes, int n_in,
                              void* d_out, int out_size, void* d_ws, size_t ws_size,
                              hipStream_t stream)
{
    if (ws_size < (size_t)WS_NEEDED) return;   // clean fail beats OOB fault

    const int*   questions = (const int*)d_in[0];
    const int*   responses = (const int*)d_in[1];
    const float* qe_w      = (const float*)d_in[2];
    const float* iv_w      = (const float*)d_in[3];
    const float* vp_w      = (const float*)d_in[4];
    const float* vp_b      = (const float*)d_in[5];
    const float* key_mem   = (const float*)d_in[6];
    const float* init_mem  = (const float*)d_in[7];
    const float* erase_w   = (const float*)d_in[8];
    const float* erase_b   = (const float*)d_in[9];
    const float* add_w     = (const float*)d_in[10];
    const float* add_b     = (const float*)d_in[11];
    const float* summary_w = (const float*)d_in[12];
    const float* summary_b = (const float*)d_in[13];
    const float* theta_w   = (const float*)d_in[14];
    const float* theta_b   = (const float*)d_in[15];
    const float* alpha_w   = (const float*)d_in[16];
    const float* alpha_b   = (const float*)d_in[17];
    const float* beta_w    = (const float*)d_in[18];
    const float* beta_b    = (const float*)d_in[19];

    char* ws = (char*)d_ws;
    float* wf    = (float*)ws;
    float* attnq = (float*)(ws + ATTNQ_OFF);
    float* preq  = (float*)(ws + PREQ_OFF);
    float* alq   = (float*)(ws + ALQ_OFF);
    float* bq    = (float*)(ws + BQ_OFF);
    float* eaq   = (float*)(ws + EAQ_OFF);
    int2v* gidx  = (int2v*)(ws + GIDX_OFF);
    u16*   Cc    = (u16*)(ws + CC_OFF);
    u16*   Dc    = (u16*)(ws + DC_OFF);
    float* out   = (float*)d_out;

    hipLaunchKernelGGL(kfront, dim3(KFRONT_NB), dim3(256), 0, stream,
        questions, responses, qe_w, iv_w, vp_w, vp_b, key_mem, summary_w,
        summary_b, alpha_w, alpha_b, beta_w, beta_b, erase_w, add_w,
        erase_b, add_b, theta_w, theta_b,
        gidx, attnq, preq, alq, bq, eaq, wf);
    hipLaunchKernelGGL(kp1, dim3((NC - 1) * BB), dim3(256), 0, stream,
        gidx, attnq, eaq, Cc, Dc);
    hipLaunchKernelGGL(kcomb, dim3(1600), dim3(256), 0, stream,
        Cc, Dc, init_mem);
    hipLaunchKernelGGL(kp2f, dim3(NC * BB), dim3(128), 0, stream,
        gidx, attnq, eaq, Cc,
        questions, wf, preq, alq, bq, out);
}

// Round 12
// 487.033 us; speedup vs baseline: 1.0961x; 1.0961x over previous
//
#include <hip/hip_runtime.h>
#include <hip/hip_bf16.h>

// ---------------- problem constants ----------------
#define BB   128
#define SS   2048
#define NPOS 262144L   // BB*SS
#define MM   50
#define DK   64
#define DV   128
#define DS   50
#define KN   5
#define NQ   1000      // distinct questions
#define NC   16        // scan chunks
#define LC   128       // SS/NC

// ---------------- workspace layout (byte offsets) ----------------
#define ATTNQ_OFF  262144L      // fp32 [1000][64] attn rows (softmaxed), cols 50..63 = 0
#define PREQ_OFF   524288L      // fp32 [1000][52] q_e-part of summary (incl. bias)
#define ALQ_OFF    786432L      // fp32 [1000] softplus alpha
#define BQ_OFF     790528L      // fp32 [1000][4] beta
#define EAQ_OFF    1048576L     // fp32 [5000][128][2] interleaved (e,a) pairs
#define GIDX_OFF   6168576L     // int2 [NPOS+6] {(q*5+r)*256, q*64}
#define READS_OFF  8388608L     // bf16 [NPOS][128]
#define CC_OFF     75497472L    // bf16 [NC][B][50][128]
#define DC_OFF     101711872L   // bf16 [NC][B][50][128]
#define WS_NEEDED  127926272L

// fp32 weight block offsets (floats) -- only what the k3-phase needs
#define SWo   12160   // summary_w TRANSPOSED [50][192]
#define TWo   21810   // theta_w [50]
#define SCo   22180   // [0]=theta_b

// kfront block ranges
#define KIDX_NB  1024
#define KQ_NB    4
#define KEAR_NB  2500
#define KPREP_NB 1
#define KFRONT_NB (KIDX_NB + KQ_NB + KEAR_NB + KPREP_NB)   // 3529

typedef unsigned short u16;
typedef __attribute__((ext_vector_type(8))) short   short8;
typedef __attribute__((ext_vector_type(4))) float   floatx4;
typedef __attribute__((ext_vector_type(2))) float   float2v;
typedef __attribute__((ext_vector_type(2))) int     int2v;

static __device__ __forceinline__ float b2f(u16 u) {
    union { unsigned int i; float f; } x; x.i = ((unsigned int)u) << 16; return x.f;
}
static __device__ __forceinline__ u16 f2b(float f) {
    union { float f; unsigned int i; } x; x.f = f;
    unsigned int i = x.i;
    return (u16)((i + 0x7fffu + ((i >> 16) & 1u)) >> 16);
}
static __device__ __forceinline__ float fast_tanh(float x) {
    float xc = fminf(15.f, fmaxf(-15.f, x));
    float t = __expf(2.f * xc);
    return (t - 1.f) / (t + 1.f);
}
static __device__ __forceinline__ float2v splat2(float x) {
    return (float2v){x, x};
}
static __device__ __forceinline__ float2v vfma(float2v a, float2v b, float2v c) {
    return __builtin_elementwise_fma(a, b, c);   // v_pk_fma_f32
}
static __device__ __forceinline__ int rfl(int x) {
    return __builtin_amdgcn_readfirstlane(x);
}

// ---------------- kfront: fused kidx + kq + kear + kprep ----------------
__global__ __launch_bounds__(256) void kfront(
    const int* __restrict__ questions, const int* __restrict__ responses,
    const float* __restrict__ qe_w, const float* __restrict__ iv_w,
    const float* __restrict__ vpw, const float* __restrict__ vpb,
    const float* __restrict__ km, const float* __restrict__ sw,
    const float* __restrict__ sb, const float* __restrict__ aw,
    const float* __restrict__ ab, const float* __restrict__ bw,
    const float* __restrict__ bb, const float* __restrict__ ew_,
    const float* __restrict__ adw_, const float* __restrict__ eb,
    const float* __restrict__ adb, const float* __restrict__ tw,
    const float* __restrict__ tb,
    int2v* __restrict__ gidx, float* __restrict__ attnq,
    float* __restrict__ preq, float* __restrict__ alq,
    float* __restrict__ bq, float* __restrict__ eaq,
    float* __restrict__ wf)
{
    int bid = blockIdx.x;
    int tid = threadIdx.x;

    if (bid < KIDX_NB) {
        // ---- kidx: per-position index table (+6 pad entries) ----
        long pos = (long)bid * 256 + tid;
        int q = questions[pos], r = responses[pos];
        int2v g = { (q * 5 + r) * 256, q * 64 };
        gidx[pos] = g;
        if (pos == NPOS - 1) {
            #pragma unroll
            for (int p = 0; p < 6; ++p) gidx[NPOS + p] = g;   // prefetch pads
        }
        return;
    }

    if (bid < KIDX_NB + KQ_NB) {
        // ---- kq: per-question tables (lane = q), raw weight reads ----
        int q = (bid - KIDX_NB) * 256 + tid;
        if (q >= NQ) return;

        float qe[64];
        const float* qrow = qe_w + (long)q * 64;
        #pragma unroll
        for (int c = 0; c < 16; ++c) {
            floatx4 vv = *(const floatx4*)(qrow + c * 4);
            qe[c*4+0] = vv[0]; qe[c*4+1] = vv[1]; qe[c*4+2] = vv[2]; qe[c*4+3] = vv[3];
        }
        float lg[50];
        #pragma unroll 2
        for (int m = 0; m < 50; ++m) {
            float acc = 0.f;
            #pragma unroll
            for (int k = 0; k < 64; ++k) acc = fmaf(qe[k], km[m * 64 + k], acc);
            lg[m] = acc;
        }
        float mx = -1e30f;
        #pragma unroll
        for (int m = 0; m < 50; ++m) mx = fmaxf(mx, lg[m]);
        float sum = 0.f;
        #pragma unroll
        for (int m = 0; m < 50; ++m) { lg[m] = __expf(lg[m] - mx); sum += lg[m]; }
        float inv = 1.f / sum;
        float* adst = attnq + q * 64;
        #pragma unroll
        for (int m = 0; m < 50; ++m) adst[m] = lg[m] * inv;
        #pragma unroll
        for (int m = 50; m < 64; ++m) adst[m] = 0.f;

        float* pdst = preq + q * 52;
        #pragma unroll 2
        for (int j = 0; j < 50; ++j) {
            float acc = sb[j];
            #pragma unroll
            for (int k = 0; k < 64; ++k)
                acc = fmaf(qe[k], sw[(128 + k) * 50 + j], acc);   // sw_t[j][128+k]
            pdst[j] = acc;
        }
        pdst[50] = 0.f; pdst[51] = 0.f;

        float al = ab[0];
        #pragma unroll
        for (int k = 0; k < 64; ++k) al = fmaf(qe[k], aw[k], al);
        alq[q] = (al > 20.f) ? al : log1pf(__expf(al));
        #pragma unroll
        for (int j = 0; j < 4; ++j) {
            float acc = bb[j];
            #pragma unroll
            for (int k = 0; k < 64; ++k) acc = fmaf(qe[k], bw[k * 4 + j], acc);
            bq[q * 4 + j] = acc;
        }
        return;
    }

    if (bid < KIDX_NB + KQ_NB + KEAR_NB) {
        // ---- kear: 2 qr rows per block, raw transposed-column reads (coalesced) ----
        __shared__ float vL[2][128];
        int half = tid >> 7;               // 0/1
        int j = tid & 127;
        int qr = (bid - KIDX_NB - KQ_NB) * 2 + half;
        int q = qr / 5, r = qr - q * 5;

        const float* irow = iv_w + (long)q * 64;       // broadcast
        float acc = vpb[j];
        #pragma unroll
        for (int k = 0; k < 64; ++k)
            acc = fmaf(irow[k], vpw[k * 128 + j], acc);          // coalesced across j
        #pragma unroll
        for (int kk = 0; kk < KN; ++kk) {
            float rf = fmaxf(1.f - fabsf((float)kk - (float)r) * 0.25f, 0.f);
            acc = fmaf(rf, vpw[(64 + kk) * 128 + j], acc);
        }
        vL[half][j] = acc;
        __syncthreads();

        float ea = eb[j], aa = adb[j];
        #pragma unroll
        for (int k = 0; k < 128; ++k) {
            float v = vL[half][k];                      // broadcast
            ea = fmaf(v, ew_[k * 128 + j], ea);         // coalesced across j
            aa = fmaf(v, adw_[k * 128 + j], aa);
        }
        float* dst = eaq + (long)qr * 256;
        dst[2 * j]     = 1.f / (1.f + __expf(-ea));   // e
        dst[2 * j + 1] = fast_tanh(aa);               // a
        return;
    }

    // ---- kprep range: k3-phase tables (sw transpose + theta) ----
    {
        for (int i = tid; i < 9600; i += 256) {           // sw_t[j][k] = sw[k][j]
            int j = i / 192, k = i - j * 192;
            wf[SWo + i] = sw[k * 50 + j];
        }
        for (int i = tid; i < 50; i += 256) wf[TWo + i] = tw[i];
        if (tid == 0) wf[SCo + 0] = tb[0];
    }
}

// ---------------- kp1: per-chunk affine transfer function ----------------
// Measured-best R8 structure (142us attractor) -- DO NOT TOUCH.
__global__ __launch_bounds__(256) __attribute__((amdgpu_waves_per_eu(5, 8)))
void kp1(
    const int2v* __restrict__ gidx, const float* __restrict__ attnq,
    const float* __restrict__ eaq,
    u16* __restrict__ Cc, u16* __restrict__ Dc)
{
    int b = blockIdx.x & (BB - 1);
    int c = blockIdx.x >> 7;
    int tid = threadIdx.x;
    int v = tid & 127;
    int mh = rfl(tid >> 7);
    int base = mh * 12;
    long tb = (long)b * SS + (long)c * LC;
    const int2v* gx = gidx + tb;

    float2v C[13], D[13];
    #pragma unroll
    for (int i = 0; i < 13; ++i) { C[i] = splat2(1.f); D[i] = splat2(0.f); }

    int eo0 = rfl(gx[0].x), ao0 = rfl(gx[0].y);
    int eo1 = rfl(gx[1].x), ao1 = rfl(gx[1].y);
    int eo2 = rfl(gx[2].x), ao2 = rfl(gx[2].y);
    int eo3 = rfl(gx[3].x), ao3 = rfl(gx[3].y);
    int eo4 = rfl(gx[4].x), ao4 = rfl(gx[4].y);
    int eo5 = rfl(gx[5].x), ao5 = rfl(gx[5].y);
    float2v ea0 = *(const float2v*)(eaq + eo0 + 2 * v);
    float2v ea1 = *(const float2v*)(eaq + eo1 + 2 * v);
    float2v ea2 = *(const float2v*)(eaq + eo2 + 2 * v);
    float2v ea3 = *(const float2v*)(eaq + eo3 + 2 * v);
    float2v wA[13], wB[13];
    {
        const float2v* a0 = (const float2v*)(attnq + ao0) + base;
        const float2v* a1 = (const float2v*)(attnq + ao1) + base;
        #pragma unroll
        for (int i = 0; i < 13; ++i) { wA[i] = a0[i]; wB[i] = a1[i]; }
    }

    for (int t = 0; t < LC; t += 2) {
        float2v ea4 = *(const float2v*)(eaq + eo4 + 2 * v);
        float2v ea5 = *(const float2v*)(eaq + eo5 + 2 * v);
        int2v g6 = gx[t + 6], g7 = gx[t + 7];
        int eo6 = rfl(g6.x), ao6 = rfl(g6.y);
        int eo7 = rfl(g7.x), ao7 = rfl(g7.y);
        const float2v* aw2 = (const float2v*)(attnq + ao2) + base;
        const float2v* aw3 = (const float2v*)(attnq + ao3) + base;
        // ---- even step: ea0, wA ----
        {
            float2v ne2 = splat2(-ea0.x), a2 = splat2(ea0.y);
            #pragma unroll
            for (int i = 0; i < 13; ++i) {
                float2v tD = vfma(ne2, D[i], a2);   // a - e*D
                float2v tC = ne2 * C[i];            // -e*C
                D[i] = vfma(wA[i], tD, D[i]);       // D + w*(a - e*D)
                C[i] = vfma(wA[i], tC, C[i]);       // C - w*e*C
            }
        }
        #pragma unroll
        for (int i = 0; i < 13; ++i) wA[i] = aw2[i];
        // ---- odd step: ea1, wB ----
        {
            float2v ne2 = splat2(-ea1.x), a2 = splat2(ea1.y);
            #pragma unroll
            for (int i = 0; i < 13; ++i) {
                float2v tD = vfma(ne2, D[i], a2);
                float2v tC = ne2 * C[i];
                D[i] = vfma(wB[i], tD, D[i]);
                C[i] = vfma(wB[i], tC, C[i]);
            }
        }
        #pragma unroll
        for (int i = 0; i < 13; ++i) wB[i] = aw3[i];
        ea0 = ea2; ea1 = ea3; ea2 = ea4; ea3 = ea5;
        ao2 = ao4; ao3 = ao5;
        eo4 = eo6; eo5 = eo7; ao4 = ao6; ao5 = ao7;
    }

    long o = ((long)(c * BB + b) * 50) * 128 + v;
    #pragma unroll
    for (int i = 0; i < 13; ++i) {
        int ii = base + i;                         // pair 12 written twice, same value
        Cc[o + (long)(2*ii)   * 128] = f2b(C[i].x);
        Cc[o + (long)(2*ii+1) * 128] = f2b(C[i].y);
        Dc[o + (long)(2*ii)   * 128] = f2b(D[i].x);
        Dc[o + (long)(2*ii+1) * 128] = f2b(D[i].y);
    }
}

// ---------------- kcomb: sequential chunk combine -> start states (into Cc) ----------------
__global__ __launch_bounds__(256) void kcomb(
    u16* __restrict__ Cc, const u16* __restrict__ Dc,
    const float* __restrict__ init_mem)
{
    long p = (long)blockIdx.x * 256 + threadIdx.x;   // over B*3200 bf16-pairs
    if (p >= (long)BB * 3200) return;
    int pv = (int)(p % 3200);
    int b  = (int)(p / 3200);
    float2v s = *(const float2v*)(init_mem + 2 * pv);
    long stride = (long)BB * 6400;
    long o = (long)b * 6400 + 2 * pv;

    unsigned int cv[NC], dv[NC];
    #pragma unroll
    for (int c = 0; c < NC; ++c) {
        cv[c] = *(const unsigned int*)(Cc + c * stride + o);
        dv[c] = *(const unsigned int*)(Dc + c * stride + o);
    }
    #pragma unroll
    for (int c = 0; c < NC; ++c) {
        float C0 = b2f((u16)(cv[c] & 0xffffu)), C1 = b2f((u16)(cv[c] >> 16));
        float D0 = b2f((u16)(dv[c] & 0xffffu)), D1 = b2f((u16)(dv[c] >> 16));
        unsigned int sp = (unsigned int)f2b(s.x) | ((unsigned int)f2b(s.y) << 16);
        *(unsigned int*)(Cc + c * stride + o) = sp;  // chunk-start state
        s.x = fmaf(C0, s.x, D0);
        s.y = fmaf(C1, s.y, D1);
    }
}

// ---------------- kp2f: replay chunk -> global reads, fused k3 epilogue ----------------
// R10 global-ws_reads structure (206us, best measured) with two register cuts:
//  * ea prefetch queue depth 3 -> 2 (ea0..3 only; in-loop loads for t+2/t+3
//    from offsets queued one iteration back -- ~400cy cover, eaq is L2/L3-hot)
//  * phase 2 chunked: acc[50] static + ch[32] per 64-wide chunk (peak ~120
//    vs 134) so phase 1 (~168) is the binding register max.
// Goal: total regs <= 170 -> 3 waves/SIMD under waves_per_eu(3,8).
__global__ __launch_bounds__(128) __attribute__((amdgpu_waves_per_eu(3, 8)))
void kp2f(
    const int2v* __restrict__ gidx, const float* __restrict__ attnq,
    const float* __restrict__ eaq,
    const u16* __restrict__ Sc, u16* __restrict__ ws_reads,
    const int* __restrict__ questions, const float* __restrict__ wf,
    const float* __restrict__ preq, const float* __restrict__ alq,
    const float* __restrict__ bq, float* __restrict__ out)
{
    __shared__ float stg[1280];          // [0,640) logits | [640,1280) probs
    int b = blockIdx.x & (BB - 1);
    int c = blockIdx.x >> 7;
    int v = threadIdx.x;
    long tb = (long)b * SS + (long)c * LC;
    const int2v* gx = gidx + tb;

    float2v M[25];
    {
        long o = ((long)(c * BB + b) * 50) * 128 + v;
        #pragma unroll
        for (int i = 0; i < 25; ++i)
            M[i] = (float2v){ b2f(Sc[o + (long)(2*i) * 128]),
                              b2f(Sc[o + (long)(2*i+1) * 128]) };
    }

    // prologue: offsets for t=0..3, ea data for t=0,1, w rows for t=0,1
    int eo0 = rfl(gx[0].x), ao0 = rfl(gx[0].y);
    int eo1 = rfl(gx[1].x), ao1 = rfl(gx[1].y);
    int eo2 = rfl(gx[2].x), ao2 = rfl(gx[2].y);
    int eo3 = rfl(gx[3].x), ao3 = rfl(gx[3].y);
    float2v ea0 = *(const float2v*)(eaq + eo0 + 2 * v);
    float2v ea1 = *(const float2v*)(eaq + eo1 + 2 * v);
    float2v wA[25], wB[25];
    {
        const float2v* a0 = (const float2v*)(attnq + ao0);
        const float2v* a1 = (const float2v*)(attnq + ao1);
        #pragma unroll
        for (int i = 0; i < 25; ++i) { wA[i] = a0[i]; wB[i] = a1[i]; }
    }

    for (int t = 0; t < LC; t += 2) {
        // ea for t+2/t+3 from offsets queued last iteration (no dep wait)
        float2v ea2 = *(const float2v*)(eaq + eo2 + 2 * v);
        float2v ea3 = *(const float2v*)(eaq + eo3 + 2 * v);
        // queue offsets for t+4/t+5
        int2v g4 = gx[t + 4], g5 = gx[t + 5];
        int eo4 = rfl(g4.x), ao4 = rfl(g4.y);
        int eo5 = rfl(g5.x), ao5 = rfl(g5.y);
        const float2v* aw2 = (const float2v*)(attnq + ao2);   // w rows t+2,t+3
        const float2v* aw3 = (const float2v*)(attnq + ao3);
        // ---- even step: ea0, wA ----
        {
            float2v ne2 = splat2(-ea0.x), a2 = splat2(ea0.y);
            float2v r0 = splat2(0.f), r1 = splat2(0.f);
            #pragma unroll
            for (int i = 0; i < 25; ++i) {
                float2v tM = vfma(ne2, M[i], a2);        // a - e*M
                if (i & 1) r1 = vfma(wA[i], M[i], r1);   // read accum (pre-update)
                else       r0 = vfma(wA[i], M[i], r0);
                M[i] = vfma(wA[i], tM, M[i]);            // M + w*(a - e*M)
            }
            float2v rs = r0 + r1;
            ws_reads[(tb + t) * 128 + v] = f2b(rs.x + rs.y);
        }
        #pragma unroll
        for (int i = 0; i < 25; ++i) wA[i] = aw2[i];     // refill for t+2
        // ---- odd step: ea1, wB ----
        {
            float2v ne2 = splat2(-ea1.x), a2 = splat2(ea1.y);
            float2v r0 = splat2(0.f), r1 = splat2(0.f);
            #pragma unroll
            for (int i = 0; i < 25; ++i) {
                float2v tM = vfma(ne2, M[i], a2);
                if (i & 1) r1 = vfma(wB[i], M[i], r1);
                else       r0 = vfma(wB[i], M[i], r0);
                M[i] = vfma(wB[i], tM, M[i]);
            }
            float2v rs = r0 + r1;
            ws_reads[(tb + t + 1) * 128 + v] = f2b(rs.x + rs.y);
        }
        #pragma unroll
        for (int i = 0; i < 25; ++i) wB[i] = aw3[i];     // refill for t+3
        // rotate queues
        ea0 = ea2; ea1 = ea3;
        eo2 = eo4; eo3 = eo5; ao2 = ao4; ao3 = ao5;
    }

    // ================= fused k3 phase =================
    __threadfence_block();          // block's global writes visible block-wide
    __syncthreads();

    long pos = tb + v;              // this thread's position
    int q = questions[pos];
    const float* swt = wf + SWo;
    const u16* rrow = ws_reads + pos * 128;   // written by this block
    const float* pq = preq + q * 52;

    float acc[50];                  // static, fully unrolled everywhere
    #pragma unroll
    for (int j = 0; j < 50; ++j) acc[j] = pq[j];

    #pragma unroll
    for (int cc = 0; cc < 2; ++cc) {          // two 64-element chunks
        float2v ch[32];
        #pragma unroll
        for (int u = 0; u < 8; ++u) {
            short8 vv = *(const short8*)(rrow + cc * 64 + u * 8);
            #pragma unroll
            for (int i = 0; i < 4; ++i)
                ch[u*4+i] = (float2v){ b2f((u16)vv[2*i]), b2f((u16)vv[2*i+1]) };
        }
        #pragma unroll 2
        for (int j = 0; j < 50; ++j) {
            const float2v* sw2 = (const float2v*)(swt + j * 192 + cc * 64);  // uniform
            float2v a2 = splat2(0.f), a3 = splat2(0.f);
            #pragma unroll
            for (int k = 0; k < 32; k += 2) {
                a2 = vfma(ch[k],     sw2[k],     a2);
                a3 = vfma(ch[k + 1], sw2[k + 1], a3);
            }
            acc[j] += a2.x + a2.y + a3.x + a3.y;
        }
    }

    float dot = 0.f;
    #pragma unroll
    for (int j = 0; j < 50; ++j)
        dot = fmaf(fast_tanh(acc[j]), wf[TWo + j], dot);

    float theta = fast_tanh(dot + wf[SCo + 0]);
    float alpha = alq[q];
    floatx4 bet = *(const floatx4*)(bq + q * 4);

    float inter = theta * alpha;
    float l1 = inter - bet[0];
    float l2 = l1 + inter - bet[1];
    float l3 = l2 + inter - bet[2];
    float l4 = l3 + inter - bet[3];
    float mx = fmaxf(0.f, fmaxf(fmaxf(l1, l2), fmaxf(l3, l4)));
    float e0 = __expf(0.f - mx), e1 = __expf(l1 - mx), e2 = __expf(l2 - mx);
    float e3 = __expf(l3 - mx), e4 = __expf(l4 - mx);
    float inv = 1.f / (e0 + e1 + e2 + e3 + e4);

    out[pos] = theta;                                   // coalesced
    out[NPOS + pos] = alpha;                            // coalesced
    *(floatx4*)(out + 2L * NPOS + pos * 4) = bet;       // dwordx4, contiguous

    stg[v * 5 + 0] = 0.f;
    stg[v * 5 + 1] = l1;  stg[v * 5 + 2] = l2;
    stg[v * 5 + 3] = l3;  stg[v * 5 + 4] = l4;
    stg[640 + v * 5 + 0] = e0 * inv;
    stg[640 + v * 5 + 1] = e1 * inv;
    stg[640 + v * 5 + 2] = e2 * inv;
    stg[640 + v * 5 + 3] = e3 * inv;
    stg[640 + v * 5 + 4] = e4 * inv;
    __syncthreads();
    float* ol = out + 6L * NPOS + tb * 5;               // block's 640-float tile
    float* op = out + 11L * NPOS + tb * 5;
    #pragma unroll
    for (int i = 0; i < 5; ++i) {
        ol[i * 128 + v] = stg[i * 128 + v];             // coalesced dwords
        op[i * 128 + v] = stg[640 + i * 128 + v];       // coalesced dwords
    }
}

// ---------------- host launcher ----------------
extern "C" void kernel_launch(void* const* d_in, const int* in_sizes, int n_in,
                              void* d_out, int out_size, void* d_ws, size_t ws_size,
                              hipStream_t stream)
{
    if (ws_size < (size_t)WS_NEEDED) return;   // clean fail beats OOB fault

    const int*   questions = (const int*)d_in[0];
    const int*   responses = (const int*)d_in[1];
    const float* qe_w      = (const float*)d_in[2];
    const float* iv_w      = (const float*)d_in[3];
    const float* vp_w      = (const float*)d_in[4];
    const float* vp_b      = (const float*)d_in[5];
    const float* key_mem   = (const float*)d_in[6];
    const float* init_mem  = (const float*)d_in[7];
    const float* erase_w   = (const float*)d_in[8];
    const float* erase_b   = (const float*)d_in[9];
    const float* add_w     = (const float*)d_in[10];
    const float* add_b     = (const float*)d_in[11];
    const float* summary_w = (const float*)d_in[12];
    const float* summary_b = (const float*)d_in[13];
    const float* theta_w   = (const float*)d_in[14];
    const float* theta_b   = (const float*)d_in[15];
    const float* alpha_w   = (const float*)d_in[16];
    const float* alpha_b   = (const float*)d_in[17];
    const float* beta_w    = (const float*)d_in[18];
    const float* beta_b    = (const float*)d_in[19];

    char* ws = (char*)d_ws;
    float* wf    = (float*)ws;
    float* attnq = (float*)(ws + ATTNQ_OFF);
    float* preq  = (float*)(ws + PREQ_OFF);
    float* alq   = (float*)(ws + ALQ_OFF);
    float* bq    = (float*)(ws + BQ_OFF);
    float* eaq   = (float*)(ws + EAQ_OFF);
    int2v* gidx  = (int2v*)(ws + GIDX_OFF);
    u16*   ws_reads = (u16*)(ws + READS_OFF);
    u16*   Cc    = (u16*)(ws + CC_OFF);
    u16*   Dc    = (u16*)(ws + DC_OFF);
    float* out   = (float*)d_out;

    hipLaunchKernelGGL(kfront, dim3(KFRONT_NB), dim3(256), 0, stream,
        questions, responses, qe_w, iv_w, vp_w, vp_b, key_mem, summary_w,
        summary_b, alpha_w, alpha_b, beta_w, beta_b, erase_w, add_w,
        erase_b, add_b, theta_w, theta_b,
        gidx, attnq, preq, alq, bq, eaq, wf);
    hipLaunchKernelGGL(kp1, dim3((NC - 1) * BB), dim3(256), 0, stream,
        gidx, attnq, eaq, Cc, Dc);
    hipLaunchKernelGGL(kcomb, dim3(1600), dim3(256), 0, stream,
        Cc, Dc, init_mem);
    hipLaunchKernelGGL(kp2f, dim3(NC * BB), dim3(128), 0, stream,
        gidx, attnq, eaq, Cc, ws_reads,
        questions, wf, preq, alq, bq, out);
}